// Round 13
// baseline (145.522 us; speedup 1.0000x reference)
//
#include <hip/hip_runtime.h>
#include <hip/hip_fp16.h>

// Problem constants (from reference)
constexpr int B = 8;
constexpr int L = 2048;
constexpr int ANG = 16;
constexpr int AMP = 48;
constexpr int H = 4;
constexpr int AQK = 12, GQK = 6;
constexpr int LOOKBACK = 100;
constexpr int NTOK = B * L;            // 16384

typedef __fp16 f16x2 __attribute__((ext_vector_type(2)));

__device__ inline f16x2 pkrtz(float a, float b) {
    return __builtin_amdgcn_cvt_pkrtz(a, b);
}
__device__ inline float2 up2(f16x2 v) { return make_float2((float)v[0], (float)v[1]); }

__device__ inline float fdot2f(f16x2 a, f16x2 b, float c) {
#if __has_builtin(__builtin_amdgcn_fdot2)
    return __builtin_amdgcn_fdot2(a, b, c, false);
#else
    return c + (float)a[0] * (float)b[0] + (float)a[1] * (float)b[1];
#endif
}

union F4H { float4 v; f16x2 h[4]; };

// ---------------- Kernel 1: QKV projections (token-parallel, R11-proven) ----------------
// h forced to SGPR via readfirstlane -> weight loads become s_load (scalar
// cache), freeing VMEM/VALU issue slots.
constexpr int QT = 64;
constexpr int QKV_BLOCKS = NTOK / QT;      // 256

__global__ __launch_bounds__(256) void qkv6_kernel(
    const float* __restrict__ x_ang, const float* __restrict__ x_amp,
    const float* __restrict__ Wq_amp, const float* __restrict__ Wk_amp,
    const float* __restrict__ Wv_amp,
    const float* __restrict__ Wq_ang_r, const float* __restrict__ Wq_ang_i,
    const float* __restrict__ Wk_ang_r, const float* __restrict__ Wk_ang_i,
    const float* __restrict__ Wv_ang_r, const float* __restrict__ Wv_ang_i,
    __fp16* __restrict__ qg, __fp16* __restrict__ kg, __fp16* __restrict__ vg)
{
    __shared__ float xs[QT][81];   // cols 0..47 amp, 48..63 ang_re, 64..79 ang_im
    const int tid  = threadIdx.x;
    const int tok0 = blockIdx.x * QT;

    {
        const float4* xm4 = (const float4*)(x_amp + (size_t)tok0 * AMP);
        for (int c = tid; c < QT * 12; c += 256) {
            int r = c / 12, i = c % 12;
            float4 t = xm4[c];
            float* p = &xs[r][4 * i];
            p[0]=t.x; p[1]=t.y; p[2]=t.z; p[3]=t.w;
        }
        const float4* xg4 = (const float4*)(x_ang + (size_t)tok0 * (2 * ANG));
        for (int c = tid; c < QT * 8; c += 256) {
            int r = c / 8, i = c % 8;
            float4 t = xg4[c];
            float* p = &xs[r][48 + 4 * i];
            p[0]=t.x; p[1]=t.y; p[2]=t.z; p[3]=t.w;
        }
    }
    __syncthreads();

    const int h  = __builtin_amdgcn_readfirstlane(tid >> 6);   // wave-uniform -> SGPR
    const int tl = tid & 63;

    // d-order: [re0..5, im0..5, amp0..11]
    float qd[24], kd[24], vd[24];
    #pragma unroll
    for (int c = 0; c < 24; ++c) { qd[c]=0.f; kd[c]=0.f; vd[c]=0.f; }

    #pragma unroll
    for (int i = 0; i < AMP; ++i) {
        float x = xs[tl][i];
        const float* wq = Wq_amp + i * 48 + h * AQK;
        const float* wk = Wk_amp + i * 48 + h * AQK;
        const float* wv = Wv_amp + i * 48 + h * AQK;
        #pragma unroll
        for (int c = 0; c < 12; ++c) {
            qd[12+c] += x * wq[c];
            kd[12+c] += x * wk[c];
            vd[12+c] += x * wv[c];
        }
    }
    #pragma unroll
    for (int i = 0; i < ANG; ++i) {
        float xr = xs[tl][48 + i], xi = xs[tl][64 + i];
        const float* wqr = Wq_ang_r + i * 24 + h * GQK;
        const float* wqi = Wq_ang_i + i * 24 + h * GQK;
        const float* wkr = Wk_ang_r + i * 24 + h * GQK;
        const float* wki = Wk_ang_i + i * 24 + h * GQK;
        const float* wvr = Wv_ang_r + i * 24 + h * GQK;
        const float* wvi = Wv_ang_i + i * 24 + h * GQK;
        #pragma unroll
        for (int c = 0; c < 6; ++c) {
            qd[c]   += xr * wqr[c] - xi * wqi[c];
            qd[6+c] += xr * wqi[c] + xi * wqr[c];
            kd[c]   += xr * wkr[c] - xi * wki[c];
            kd[6+c] += xr * wki[c] + xi * wkr[c];
            vd[c]   += xr * wvr[c] - xi * wvi[c];
            vd[6+c] += xr * wvi[c] + xi * wvr[c];
        }
    }

    const int bb = tok0 / L;               // whole block in one b (L % QT == 0)
    const int ll = (tok0 % L) + tl;
    const size_t row = ((size_t)(bb * H + h) * L + ll) * 3;   // float4 units
    #pragma unroll
    for (int sl = 0; sl < 3; ++sl) {
        F4H fq, fk, fv;
        #pragma unroll
        for (int j = 0; j < 4; ++j) {
            fq.h[j] = pkrtz(qd[8*sl + 2*j], qd[8*sl + 2*j + 1]);
            fk.h[j] = pkrtz(kd[8*sl + 2*j], kd[8*sl + 2*j + 1]);
            fv.h[j] = pkrtz(vd[8*sl + 2*j], vd[8*sl + 2*j + 1]);
        }
        ((float4*)qg)[row + sl] = fq.v;
        ((float4*)kg)[row + sl] = fk.v;
        ((float4*)vg)[row + sl] = fv.v;
    }
}

// ---------------- Kernel 2: fused banded attention + output projection ----------------
// Block = (b, 32-query tile), ALL 4 heads. 512 thr = 8 waves = 4 heads x 2
// query-halves. Attention core unchanged (R11/R12-proven). Epilogue re-mapped
// to proj4-style float4 weight loads: waves 0..5 = amp (tok x 12 col4),
// waves 6..7 = ang (tok x 4 col4) -> 48 vector VMEM/thread instead of ~240
// scalar loads.
constexpr int TQ2    = 32;
constexpr int GROUPS = 4;
constexpr int CHUNK  = 25;                  // ceil(LOOKBACK/GROUPS)
constexpr int MAXK2  = TQ2 + LOOKBACK - 1;  // 131
constexpr int NT2    = L / TQ2;             // 64

__global__ __launch_bounds__(512, 2) void attn_proj_kernel(
    const __fp16* __restrict__ qg, const __fp16* __restrict__ kg,
    const __fp16* __restrict__ vg,
    const float* __restrict__ Wout_amp, const float* __restrict__ bout_amp,
    const float* __restrict__ Wout_ang_r, const float* __restrict__ Wout_ang_i,
    float* __restrict__ out)
{
    __shared__ float4 Ks[H][MAXK2][3];
    __shared__ float4 Vs[H][MAXK2][3];
    __shared__ float  att_s[TQ2][100];      // [ql][h*24 + d]

    const int tid = threadIdx.x;
    const int b   = blockIdx.x >> 6;        // NT2 = 64
    const int qt  = blockIdx.x & 63;
    const int q0  = qt * TQ2;
    int kmin = q0 - (LOOKBACK - 1); if (kmin < 0) kmin = 0;

    // ---- stage K/V for all 4 heads (full 131 rows, always in-bounds) ----
    {
        const float4* kb = (const float4*)kg;
        const float4* vb = (const float4*)vg;
        for (int c = tid; c < H * MAXK2 * 3; c += 512) {
            int hh  = c / (MAXK2 * 3);
            int rem = c % (MAXK2 * 3);
            int r   = rem / 3, sl = rem % 3;
            size_t gi = ((size_t)(b * H + hh) * L + kmin + r) * 3 + sl;
            Ks[hh][r][sl] = kb[gi];
            Vs[hh][r][sl] = vb[gi];
        }
    }
    __syncthreads();

    // ---- attention (per-wave: head h, query-half qh) ----
    const int ww   = tid >> 6;              // wave 0..7
    const int lane = tid & 63;
    const int h    = __builtin_amdgcn_readfirstlane(ww & 3);   // wave-uniform head
    const int qh   = __builtin_amdgcn_readfirstlane(ww >> 2);  // 0/1
    const int q16  = lane & 15;
    const int g    = lane >> 4;             // split-K group 0..3
    const int ql   = qh * 16 + q16;
    const int qi   = q0 + ql;

    f16x2 qhv[12];
    {
        const float4* qrow = (const float4*)qg + ((size_t)(b * H + h) * L + qi) * 3;
        F4H a0, a1, a2;
        a0.v = qrow[0]; a1.v = qrow[1]; a2.v = qrow[2];
        #pragma unroll
        for (int j = 0; j < 4; ++j) {
            qhv[j] = a0.h[j]; qhv[4 + j] = a1.h[j]; qhv[8 + j] = a2.h[j];
        }
    }

    const float scale = 0.2041241452319315f; // 1/sqrt(24)
    int j0 = qi - (LOOKBACK - 1); if (j0 < 0) j0 = 0;
    const int jstart = j0 + g;

    float sc[CHUNK];
    #pragma unroll
    for (int t = 0; t < CHUNK; ++t) {
        int j = jstart + t * GROUPS;
        int r = j - kmin;
        F4H k0, k1, k2;
        k0.v = Ks[h][r][0]; k1.v = Ks[h][r][1]; k2.v = Ks[h][r][2];
        float d = 0.f;
        #pragma unroll
        for (int jj = 0; jj < 4; ++jj) d = fdot2f(qhv[jj],     k0.h[jj], d);
        #pragma unroll
        for (int jj = 0; jj < 4; ++jj) d = fdot2f(qhv[4 + jj], k1.h[jj], d);
        #pragma unroll
        for (int jj = 0; jj < 4; ++jj) d = fdot2f(qhv[8 + jj], k2.h[jj], d);
        sc[t] = (j <= qi) ? d * scale : -3.0e38f;
    }
    float m = sc[0];
    #pragma unroll
    for (int t = 1; t < CHUNK; ++t) m = fmaxf(m, sc[t]);
    float ssum = 0.f;
    #pragma unroll
    for (int t = 0; t < CHUNK; ++t) {
        float p = __expf(sc[t] - m);
        p = (sc[t] > -1.0e37f) ? p : 0.f;
        sc[t] = p;
        ssum += p;
    }
    float o[24];
    #pragma unroll
    for (int e = 0; e < 24; ++e) o[e] = 0.f;
    #pragma unroll
    for (int t = 0; t < CHUNK; ++t) {
        float p = sc[t];
        int j = jstart + t * GROUPS;
        int r = j - kmin;
        #pragma unroll
        for (int sl = 0; sl < 3; ++sl) {
            F4H vv; vv.v = Vs[h][r][sl];
            #pragma unroll
            for (int jj = 0; jj < 4; ++jj) {
                float2 a = up2(vv.h[jj]);          // folds to v_fma_mix
                o[8*sl + 2*jj]     += p * a.x;
                o[8*sl + 2*jj + 1] += p * a.y;
            }
        }
    }

    // merge across the 4 groups (lanes xor 16, xor 32) — exact algebra
    #pragma unroll
    for (int d = 16; d <= 32; d <<= 1) {
        float m2 = __shfl_xor(m, d);
        float s2 = __shfl_xor(ssum, d);
        float mm = fmaxf(m, m2);
        float c1 = __expf(m - mm);
        float c2 = __expf(m2 - mm);
        ssum = ssum * c1 + s2 * c2;
        #pragma unroll
        for (int e = 0; e < 24; ++e)
            o[e] = o[e] * c1 + __shfl_xor(o[e], d) * c2;
        m = mm;
    }
    float inv = 1.f / ssum;

    // write att_s[ql][h*24 + d] = o[d]*inv ; duplicate lanes split 6 slots
    {
        float* arow = &att_s[ql][h * 24];
        if (g == 0) {
            *(float4*)(arow +  0) = make_float4(o[0]*inv,  o[1]*inv,  o[2]*inv,  o[3]*inv);
            *(float4*)(arow + 16) = make_float4(o[16]*inv, o[17]*inv, o[18]*inv, o[19]*inv);
        } else if (g == 1) {
            *(float4*)(arow +  4) = make_float4(o[4]*inv,  o[5]*inv,  o[6]*inv,  o[7]*inv);
            *(float4*)(arow + 20) = make_float4(o[20]*inv, o[21]*inv, o[22]*inv, o[23]*inv);
        } else if (g == 2) {
            *(float4*)(arow +  8) = make_float4(o[8]*inv,  o[9]*inv,  o[10]*inv, o[11]*inv);
        } else {
            *(float4*)(arow + 12) = make_float4(o[12]*inv, o[13]*inv, o[14]*inv, o[15]*inv);
        }
    }
    __syncthreads();

    // ---- output projection (proj4-style, float4 weight loads) ----
    // waves 0..5 (384 thr): amp — unit = (tok, c4 in 0..11), 4 cols each
    // waves 6..7 (128 thr): ang — unit = (tok, c4 in 0..3), 4 cols r & i
    {
        constexpr size_t ANG_OUT = (size_t)NTOK * ANG; // 262144
        if (tid < 384) {
            const int tok = tid / 12;          // 0..31
            const int c4  = (tid % 12) * 4;    // 0..44
            const float* arow = att_s[tok];

            float a[48];
            #pragma unroll
            for (int h2 = 0; h2 < H; ++h2) {
                const float4* ap = (const float4*)(arow + h2 * 24 + 12);
                #pragma unroll
                for (int i = 0; i < 3; ++i) {
                    float4 t = ap[i];
                    a[h2*12 + 4*i+0]=t.x; a[h2*12 + 4*i+1]=t.y;
                    a[h2*12 + 4*i+2]=t.z; a[h2*12 + 4*i+3]=t.w;
                }
            }
            float4 acc = *(const float4*)(bout_amp + c4);
            #pragma unroll
            for (int i = 0; i < 48; ++i) {
                float4 w = *(const float4*)(Wout_amp + i * 48 + c4);
                acc.x += a[i]*w.x; acc.y += a[i]*w.y;
                acc.z += a[i]*w.z; acc.w += a[i]*w.w;
            }
            const size_t tokg = (size_t)b * L + q0 + tok;
            *(float4*)(out + 2*ANG_OUT + tokg * 48 + c4) = acc;
        } else {
            const int unit = tid - 384;
            const int tok  = unit >> 2;        // 0..31
            const int c4   = (unit & 3) * 4;   // 0,4,8,12
            const float* arow = att_s[tok];

            float ar[24], ai[24];
            #pragma unroll
            for (int h2 = 0; h2 < H; ++h2) {
                const float4* ap = (const float4*)(arow + h2 * 24);
                float4 t0 = ap[0], t1 = ap[1], t2 = ap[2];
                ar[h2*6+0]=t0.x; ar[h2*6+1]=t0.y; ar[h2*6+2]=t0.z; ar[h2*6+3]=t0.w;
                ar[h2*6+4]=t1.x; ar[h2*6+5]=t1.y;
                ai[h2*6+0]=t1.z; ai[h2*6+1]=t1.w;
                ai[h2*6+2]=t2.x; ai[h2*6+3]=t2.y; ai[h2*6+4]=t2.z; ai[h2*6+5]=t2.w;
            }
            float4 accr = make_float4(0.f,0.f,0.f,0.f);
            float4 acci = make_float4(0.f,0.f,0.f,0.f);
            #pragma unroll
            for (int i = 0; i < 24; ++i) {
                float4 wr = *(const float4*)(Wout_ang_r + i * 16 + c4);
                float4 wi = *(const float4*)(Wout_ang_i + i * 16 + c4);
                float r = ar[i], im = ai[i];
                accr.x += r*wr.x - im*wi.x;  accr.y += r*wr.y - im*wi.y;
                accr.z += r*wr.z - im*wi.z;  accr.w += r*wr.w - im*wi.w;
                acci.x += r*wi.x + im*wr.x;  acci.y += r*wi.y + im*wr.y;
                acci.z += r*wi.z + im*wr.z;  acci.w += r*wi.w + im*wr.w;
            }
            const size_t tokg = (size_t)b * L + q0 + tok;
            *(float4*)(out + tokg * 16 + c4)           = accr;
            *(float4*)(out + ANG_OUT + tokg * 16 + c4) = acci;
        }
    }
}

// -------------------- Launch --------------------
extern "C" void kernel_launch(void* const* d_in, const int* in_sizes, int n_in,
                              void* d_out, int out_size, void* d_ws, size_t ws_size,
                              hipStream_t stream)
{
    const float* x_ang      = (const float*)d_in[0];
    const float* x_amp      = (const float*)d_in[1];
    const float* Wq_amp     = (const float*)d_in[2];
    const float* Wk_amp     = (const float*)d_in[3];
    const float* Wv_amp     = (const float*)d_in[4];
    const float* Wq_ang_r   = (const float*)d_in[5];
    const float* Wq_ang_i   = (const float*)d_in[6];
    const float* Wk_ang_r   = (const float*)d_in[7];
    const float* Wk_ang_i   = (const float*)d_in[8];
    const float* Wv_ang_r   = (const float*)d_in[9];
    const float* Wv_ang_i   = (const float*)d_in[10];
    const float* Wout_amp   = (const float*)d_in[11];
    const float* bout_amp   = (const float*)d_in[12];
    const float* Wout_ang_r = (const float*)d_in[13];
    const float* Wout_ang_i = (const float*)d_in[14];

    float* out = (float*)d_out;

    const size_t NQKV = (size_t)NTOK * H * 24;       // 1,572,864 halves each
    __fp16* qg = (__fp16*)d_ws;
    __fp16* kg = qg + NQKV;
    __fp16* vg = kg + NQKV;

    qkv6_kernel<<<QKV_BLOCKS, 256, 0, stream>>>(
        x_ang, x_amp, Wq_amp, Wk_amp, Wv_amp,
        Wq_ang_r, Wq_ang_i, Wk_ang_r, Wk_ang_i, Wv_ang_r, Wv_ang_i,
        qg, kg, vg);

    attn_proj_kernel<<<B * NT2, 512, 0, stream>>>(
        qg, kg, vg, Wout_amp, bout_amp, Wout_ang_r, Wout_ang_i, out);
}

// Round 16
// 136.602 us; speedup vs baseline: 1.0653x; 1.0653x over previous
//
#include <hip/hip_runtime.h>
#include <hip/hip_fp16.h>

// Problem constants (from reference)
constexpr int B = 8;
constexpr int L = 2048;
constexpr int ANG = 16;
constexpr int AMP = 48;
constexpr int H = 4;
constexpr int AQK = 12, GQK = 6;
constexpr int LOOKBACK = 100;
constexpr int NTOK = B * L;            // 16384

typedef __fp16 f16x2 __attribute__((ext_vector_type(2)));

__device__ inline f16x2 pkrtz(float a, float b) {
    return __builtin_amdgcn_cvt_pkrtz(a, b);
}
__device__ inline float2 up2(f16x2 v) { return make_float2((float)v[0], (float)v[1]); }

__device__ inline float fdot2f(f16x2 a, f16x2 b, float c) {
#if __has_builtin(__builtin_amdgcn_fdot2)
    return __builtin_amdgcn_fdot2(a, b, c, false);
#else
    return c + (float)a[0] * (float)b[0] + (float)a[1] * (float)b[1];
#endif
}

union F4H { float4 v; f16x2 h[4]; };

// ---------------- Kernel 1: QKV projections (token-parallel, R11-proven) ----------------
constexpr int QT = 64;
constexpr int QKV_BLOCKS = NTOK / QT;      // 256

__global__ __launch_bounds__(256) void qkv6_kernel(
    const float* __restrict__ x_ang, const float* __restrict__ x_amp,
    const float* __restrict__ Wq_amp, const float* __restrict__ Wk_amp,
    const float* __restrict__ Wv_amp,
    const float* __restrict__ Wq_ang_r, const float* __restrict__ Wq_ang_i,
    const float* __restrict__ Wk_ang_r, const float* __restrict__ Wk_ang_i,
    const float* __restrict__ Wv_ang_r, const float* __restrict__ Wv_ang_i,
    __fp16* __restrict__ qg, __fp16* __restrict__ kg, __fp16* __restrict__ vg)
{
    __shared__ float xs[QT][81];   // cols 0..47 amp, 48..63 ang_re, 64..79 ang_im
    const int tid  = threadIdx.x;
    const int tok0 = blockIdx.x * QT;

    {
        const float4* xm4 = (const float4*)(x_amp + (size_t)tok0 * AMP);
        for (int c = tid; c < QT * 12; c += 256) {
            int r = c / 12, i = c % 12;
            float4 t = xm4[c];
            float* p = &xs[r][4 * i];
            p[0]=t.x; p[1]=t.y; p[2]=t.z; p[3]=t.w;
        }
        const float4* xg4 = (const float4*)(x_ang + (size_t)tok0 * (2 * ANG));
        for (int c = tid; c < QT * 8; c += 256) {
            int r = c / 8, i = c % 8;
            float4 t = xg4[c];
            float* p = &xs[r][48 + 4 * i];
            p[0]=t.x; p[1]=t.y; p[2]=t.z; p[3]=t.w;
        }
    }
    __syncthreads();

    const int h  = tid >> 6;       // wave-uniform
    const int tl = tid & 63;

    // d-order: [re0..5, im0..5, amp0..11]
    float qd[24], kd[24], vd[24];
    #pragma unroll
    for (int c = 0; c < 24; ++c) { qd[c]=0.f; kd[c]=0.f; vd[c]=0.f; }

    #pragma unroll
    for (int i = 0; i < AMP; ++i) {
        float x = xs[tl][i];
        const float* wq = Wq_amp + i * 48 + h * AQK;
        const float* wk = Wk_amp + i * 48 + h * AQK;
        const float* wv = Wv_amp + i * 48 + h * AQK;
        #pragma unroll
        for (int c = 0; c < 12; ++c) {
            qd[12+c] += x * wq[c];
            kd[12+c] += x * wk[c];
            vd[12+c] += x * wv[c];
        }
    }
    #pragma unroll
    for (int i = 0; i < ANG; ++i) {
        float xr = xs[tl][48 + i], xi = xs[tl][64 + i];
        const float* wqr = Wq_ang_r + i * 24 + h * GQK;
        const float* wqi = Wq_ang_i + i * 24 + h * GQK;
        const float* wkr = Wk_ang_r + i * 24 + h * GQK;
        const float* wki = Wk_ang_i + i * 24 + h * GQK;
        const float* wvr = Wv_ang_r + i * 24 + h * GQK;
        const float* wvi = Wv_ang_i + i * 24 + h * GQK;
        #pragma unroll
        for (int c = 0; c < 6; ++c) {
            qd[c]   += xr * wqr[c] - xi * wqi[c];
            qd[6+c] += xr * wqi[c] + xi * wqr[c];
            kd[c]   += xr * wkr[c] - xi * wki[c];
            kd[6+c] += xr * wki[c] + xi * wkr[c];
            vd[c]   += xr * wvr[c] - xi * wvi[c];
            vd[6+c] += xr * wvi[c] + xi * wvr[c];
        }
    }

    const int bb = tok0 / L;               // whole block in one b (L % QT == 0)
    const int ll = (tok0 % L) + tl;
    const size_t row = ((size_t)(bb * H + h) * L + ll) * 3;   // float4 units
    #pragma unroll
    for (int sl = 0; sl < 3; ++sl) {
        F4H fq, fk, fv;
        #pragma unroll
        for (int j = 0; j < 4; ++j) {
            fq.h[j] = pkrtz(qd[8*sl + 2*j], qd[8*sl + 2*j + 1]);
            fk.h[j] = pkrtz(kd[8*sl + 2*j], kd[8*sl + 2*j + 1]);
            fv.h[j] = pkrtz(vd[8*sl + 2*j], vd[8*sl + 2*j + 1]);
        }
        ((float4*)qg)[row + sl] = fq.v;
        ((float4*)kg)[row + sl] = fk.v;
        ((float4*)vg)[row + sl] = fv.v;
    }
}

// ---------------- Kernel 2: fused banded attention + output projection ----------------
// Block = (b, 32-query tile), ALL 4 heads. 512 thr = 8 waves = 4 heads x 2
// query-halves. Per-wave attention = attn7 core (16 q x 4 split-K groups,
// two-pass softmax, fdot2 QK, fma_mix PV, shfl_xor merge). Merged outputs ->
// att_s[32][100] LDS, then the block computes all 80 outputs per token
// (thread = (tok, s): ang_r[s], ang_i[s], amp[s], amp[s+16], amp[s+32]).
// All 131 staged rows are in-bounds real data; out-of-band keys masked via sc.
constexpr int TQ2    = 32;
constexpr int GROUPS = 4;
constexpr int CHUNK  = 25;                  // ceil(LOOKBACK/GROUPS)
constexpr int MAXK2  = TQ2 + LOOKBACK - 1;  // 131
constexpr int NT2    = L / TQ2;             // 64

__global__ __launch_bounds__(512, 2) void attn_proj_kernel(
    const __fp16* __restrict__ qg, const __fp16* __restrict__ kg,
    const __fp16* __restrict__ vg,
    const float* __restrict__ Wout_amp, const float* __restrict__ bout_amp,
    const float* __restrict__ Wout_ang_r, const float* __restrict__ Wout_ang_i,
    float* __restrict__ out)
{
    __shared__ float4 Ks[H][MAXK2][3];
    __shared__ float4 Vs[H][MAXK2][3];
    __shared__ float  att_s[TQ2][100];      // [ql][h*24 + d]

    const int tid = threadIdx.x;
    const int b   = blockIdx.x >> 6;        // NT2 = 64
    const int qt  = blockIdx.x & 63;
    const int q0  = qt * TQ2;
    int kmin = q0 - (LOOKBACK - 1); if (kmin < 0) kmin = 0;

    // ---- stage K/V for all 4 heads (full 131 rows, always in-bounds) ----
    {
        const float4* kb = (const float4*)kg;
        const float4* vb = (const float4*)vg;
        for (int c = tid; c < H * MAXK2 * 3; c += 512) {
            int hh  = c / (MAXK2 * 3);
            int rem = c % (MAXK2 * 3);
            int r   = rem / 3, sl = rem % 3;
            size_t gi = ((size_t)(b * H + hh) * L + kmin + r) * 3 + sl;
            Ks[hh][r][sl] = kb[gi];
            Vs[hh][r][sl] = vb[gi];
        }
    }
    __syncthreads();

    // ---- attention (per-wave: head h, query-half qh) ----
    const int ww   = tid >> 6;              // wave 0..7
    const int lane = tid & 63;
    const int h    = ww & 3;                // wave-uniform head
    const int qh   = ww >> 2;               // 0/1
    const int q16  = lane & 15;
    const int g    = lane >> 4;             // split-K group 0..3
    const int ql   = qh * 16 + q16;
    const int qi   = q0 + ql;

    f16x2 qhv[12];
    {
        const float4* qrow = (const float4*)qg + ((size_t)(b * H + h) * L + qi) * 3;
        F4H a0, a1, a2;
        a0.v = qrow[0]; a1.v = qrow[1]; a2.v = qrow[2];
        #pragma unroll
        for (int j = 0; j < 4; ++j) {
            qhv[j] = a0.h[j]; qhv[4 + j] = a1.h[j]; qhv[8 + j] = a2.h[j];
        }
    }

    const float scale = 0.2041241452319315f; // 1/sqrt(24)
    int j0 = qi - (LOOKBACK - 1); if (j0 < 0) j0 = 0;
    const int jstart = j0 + g;

    float sc[CHUNK];
    #pragma unroll
    for (int t = 0; t < CHUNK; ++t) {
        int j = jstart + t * GROUPS;
        int r = j - kmin;
        F4H k0, k1, k2;
        k0.v = Ks[h][r][0]; k1.v = Ks[h][r][1]; k2.v = Ks[h][r][2];
        float d = 0.f;
        #pragma unroll
        for (int jj = 0; jj < 4; ++jj) d = fdot2f(qhv[jj],     k0.h[jj], d);
        #pragma unroll
        for (int jj = 0; jj < 4; ++jj) d = fdot2f(qhv[4 + jj], k1.h[jj], d);
        #pragma unroll
        for (int jj = 0; jj < 4; ++jj) d = fdot2f(qhv[8 + jj], k2.h[jj], d);
        sc[t] = (j <= qi) ? d * scale : -3.0e38f;
    }
    float m = sc[0];
    #pragma unroll
    for (int t = 1; t < CHUNK; ++t) m = fmaxf(m, sc[t]);
    float ssum = 0.f;
    #pragma unroll
    for (int t = 0; t < CHUNK; ++t) {
        float p = __expf(sc[t] - m);
        p = (sc[t] > -1.0e37f) ? p : 0.f;
        sc[t] = p;
        ssum += p;
    }
    float o[24];
    #pragma unroll
    for (int e = 0; e < 24; ++e) o[e] = 0.f;
    #pragma unroll
    for (int t = 0; t < CHUNK; ++t) {
        float p = sc[t];
        int j = jstart + t * GROUPS;
        int r = j - kmin;
        #pragma unroll
        for (int sl = 0; sl < 3; ++sl) {
            F4H vv; vv.v = Vs[h][r][sl];
            #pragma unroll
            for (int jj = 0; jj < 4; ++jj) {
                float2 a = up2(vv.h[jj]);          // folds to v_fma_mix
                o[8*sl + 2*jj]     += p * a.x;
                o[8*sl + 2*jj + 1] += p * a.y;
            }
        }
    }

    // merge across the 4 groups (lanes xor 16, xor 32) — exact algebra
    #pragma unroll
    for (int d = 16; d <= 32; d <<= 1) {
        float m2 = __shfl_xor(m, d);
        float s2 = __shfl_xor(ssum, d);
        float mm = fmaxf(m, m2);
        float c1 = __expf(m - mm);
        float c2 = __expf(m2 - mm);
        ssum = ssum * c1 + s2 * c2;
        #pragma unroll
        for (int e = 0; e < 24; ++e)
            o[e] = o[e] * c1 + __shfl_xor(o[e], d) * c2;
        m = mm;
    }
    float inv = 1.f / ssum;

    // write att_s[ql][h*24 + d] = o[d]*inv ; duplicate lanes split 6 slots
    {
        float* arow = &att_s[ql][h * 24];
        if (g == 0) {
            *(float4*)(arow +  0) = make_float4(o[0]*inv,  o[1]*inv,  o[2]*inv,  o[3]*inv);
            *(float4*)(arow + 16) = make_float4(o[16]*inv, o[17]*inv, o[18]*inv, o[19]*inv);
        } else if (g == 1) {
            *(float4*)(arow +  4) = make_float4(o[4]*inv,  o[5]*inv,  o[6]*inv,  o[7]*inv);
            *(float4*)(arow + 20) = make_float4(o[20]*inv, o[21]*inv, o[22]*inv, o[23]*inv);
        } else if (g == 2) {
            *(float4*)(arow +  8) = make_float4(o[8]*inv,  o[9]*inv,  o[10]*inv, o[11]*inv);
        } else {
            *(float4*)(arow + 12) = make_float4(o[12]*inv, o[13]*inv, o[14]*inv, o[15]*inv);
        }
    }
    __syncthreads();

    // ---- output projection: thread = (tok, s); 5 outputs ----
    {
        constexpr size_t ANG_OUT = (size_t)NTOK * ANG; // 262144
        const int tok = tid >> 4;          // 0..31
        const int s   = tid & 15;          // 0..15
        const float* arow = att_s[tok];
        const size_t tokg = (size_t)b * L + q0 + tok;

        float accr = 0.f, acci = 0.f;
        #pragma unroll
        for (int h2 = 0; h2 < H; ++h2) {
            #pragma unroll
            for (int c = 0; c < 6; ++c) {
                float ar = arow[h2*24 + c], ai = arow[h2*24 + 6 + c];
                int rw = h2 * 6 + c;
                float wr = Wout_ang_r[rw * 16 + s];
                float wi = Wout_ang_i[rw * 16 + s];
                accr += ar * wr - ai * wi;
                acci += ar * wi + ai * wr;
            }
        }
        out[tokg * 16 + s]           = accr;
        out[ANG_OUT + tokg * 16 + s] = acci;

        float a0 = bout_amp[s], a1 = bout_amp[s + 16], a2 = bout_amp[s + 32];
        #pragma unroll
        for (int h2 = 0; h2 < H; ++h2) {
            #pragma unroll
            for (int c = 0; c < 12; ++c) {
                float xa = arow[h2*24 + 12 + c];
                const float* wrow = Wout_amp + (h2 * 12 + c) * 48;
                a0 += xa * wrow[s];
                a1 += xa * wrow[s + 16];
                a2 += xa * wrow[s + 32];
            }
        }
        float* ob = out + 2 * ANG_OUT + tokg * 48;
        ob[s]      = a0;
        ob[s + 16] = a1;
        ob[s + 32] = a2;
    }
}

// -------------------- Launch --------------------
extern "C" void kernel_launch(void* const* d_in, const int* in_sizes, int n_in,
                              void* d_out, int out_size, void* d_ws, size_t ws_size,
                              hipStream_t stream)
{
    const float* x_ang      = (const float*)d_in[0];
    const float* x_amp      = (const float*)d_in[1];
    const float* Wq_amp     = (const float*)d_in[2];
    const float* Wk_amp     = (const float*)d_in[3];
    const float* Wv_amp     = (const float*)d_in[4];
    const float* Wq_ang_r   = (const float*)d_in[5];
    const float* Wq_ang_i   = (const float*)d_in[6];
    const float* Wk_ang_r   = (const float*)d_in[7];
    const float* Wk_ang_i   = (const float*)d_in[8];
    const float* Wv_ang_r   = (const float*)d_in[9];
    const float* Wv_ang_i   = (const float*)d_in[10];
    const float* Wout_amp   = (const float*)d_in[11];
    const float* bout_amp   = (const float*)d_in[12];
    const float* Wout_ang_r = (const float*)d_in[13];
    const float* Wout_ang_i = (const float*)d_in[14];

    float* out = (float*)d_out;

    const size_t NQKV = (size_t)NTOK * H * 24;       // 1,572,864 halves each
    __fp16* qg = (__fp16*)d_ws;
    __fp16* kg = qg + NQKV;
    __fp16* vg = kg + NQKV;

    qkv6_kernel<<<QKV_BLOCKS, 256, 0, stream>>>(
        x_ang, x_amp, Wq_amp, Wk_amp, Wv_amp,
        Wq_ang_r, Wq_ang_i, Wk_ang_r, Wk_ang_i, Wv_ang_r, Wv_ang_i,
        qg, kg, vg);

    attn_proj_kernel<<<B * NT2, 512, 0, stream>>>(
        qg, kg, vg, Wout_amp, bout_amp, Wout_ang_r, Wout_ang_i, out);
}

// Round 17
// 135.472 us; speedup vs baseline: 1.0742x; 1.0083x over previous
//
#include <hip/hip_runtime.h>
#include <hip/hip_fp16.h>

// Problem constants (from reference)
constexpr int B = 8;
constexpr int L = 2048;
constexpr int ANG = 16;
constexpr int AMP = 48;
constexpr int H = 4;
constexpr int AQK = 12, GQK = 6;
constexpr int LOOKBACK = 100;
constexpr int NTOK = B * L;            // 16384

typedef __fp16 f16x2 __attribute__((ext_vector_type(2)));

__device__ inline f16x2 pkrtz(float a, float b) {
    return __builtin_amdgcn_cvt_pkrtz(a, b);
}
__device__ inline float2 up2(f16x2 v) { return make_float2((float)v[0], (float)v[1]); }

__device__ inline float fdot2f(f16x2 a, f16x2 b, float c) {
#if __has_builtin(__builtin_amdgcn_fdot2)
    return __builtin_amdgcn_fdot2(a, b, c, false);
#else
    return c + (float)a[0] * (float)b[0] + (float)a[1] * (float)b[1];
#endif
}

union F4H { float4 v; f16x2 h[4]; };

// ---------------- Kernel 1: QKV projections (split-matrix for occupancy) ----------------
// R16 measured: 256-block version = 1 block/CU, 10% occupancy, 10% VALUBusy,
// 52-58 us (latency-bound). Fix: mat = blockIdx.x % 3 (0=q,1=k,2=v) -> 768
// blocks = 3 blocks/CU = 12 waves/CU; each thread computes 24 outputs of ONE
// matrix (~960 MACs), 3x shorter chain, lower VGPR. x re-staged per mat
// (52 KB/block, L2-hot).
constexpr int QT = 64;
constexpr int QKV_TOKBLOCKS = NTOK / QT;        // 256
constexpr int QKV_BLOCKS = 3 * QKV_TOKBLOCKS;   // 768

__global__ __launch_bounds__(256) void qkv7_kernel(
    const float* __restrict__ x_ang, const float* __restrict__ x_amp,
    const float* __restrict__ Wq_amp, const float* __restrict__ Wk_amp,
    const float* __restrict__ Wv_amp,
    const float* __restrict__ Wq_ang_r, const float* __restrict__ Wq_ang_i,
    const float* __restrict__ Wk_ang_r, const float* __restrict__ Wk_ang_i,
    const float* __restrict__ Wv_ang_r, const float* __restrict__ Wv_ang_i,
    __fp16* __restrict__ qg, __fp16* __restrict__ kg, __fp16* __restrict__ vg)
{
    __shared__ float xs[QT][81];   // cols 0..47 amp, 48..63 ang_re, 64..79 ang_im
    const int tid  = threadIdx.x;
    const int mat  = blockIdx.x % 3;                 // 0=q 1=k 2=v (block-uniform)
    const int tok0 = (blockIdx.x / 3) * QT;

    {
        const float4* xm4 = (const float4*)(x_amp + (size_t)tok0 * AMP);
        for (int c = tid; c < QT * 12; c += 256) {
            int r = c / 12, i = c % 12;
            float4 t = xm4[c];
            float* p = &xs[r][4 * i];
            p[0]=t.x; p[1]=t.y; p[2]=t.z; p[3]=t.w;
        }
        const float4* xg4 = (const float4*)(x_ang + (size_t)tok0 * (2 * ANG));
        for (int c = tid; c < QT * 8; c += 256) {
            int r = c / 8, i = c % 8;
            float4 t = xg4[c];
            float* p = &xs[r][48 + 4 * i];
            p[0]=t.x; p[1]=t.y; p[2]=t.z; p[3]=t.w;
        }
    }
    __syncthreads();

    const float* Wamp = (mat == 0) ? Wq_amp   : (mat == 1) ? Wk_amp   : Wv_amp;
    const float* Wanr = (mat == 0) ? Wq_ang_r : (mat == 1) ? Wk_ang_r : Wv_ang_r;
    const float* Wani = (mat == 0) ? Wq_ang_i : (mat == 1) ? Wk_ang_i : Wv_ang_i;
    __fp16*      dstg = (mat == 0) ? qg       : (mat == 1) ? kg       : vg;

    const int h  = tid >> 6;       // wave-uniform
    const int tl = tid & 63;

    // d-order: [re0..5, im0..5, amp0..11]
    float d[24];
    #pragma unroll
    for (int c = 0; c < 24; ++c) d[c] = 0.f;

    #pragma unroll
    for (int i = 0; i < AMP; ++i) {
        float x = xs[tl][i];
        const float* w = Wamp + i * 48 + h * AQK;
        #pragma unroll
        for (int c = 0; c < 12; ++c) d[12 + c] += x * w[c];
    }
    #pragma unroll
    for (int i = 0; i < ANG; ++i) {
        float xr = xs[tl][48 + i], xi = xs[tl][64 + i];
        const float* wr = Wanr + i * 24 + h * GQK;
        const float* wi = Wani + i * 24 + h * GQK;
        #pragma unroll
        for (int c = 0; c < 6; ++c) {
            d[c]     += xr * wr[c] - xi * wi[c];
            d[6 + c] += xr * wi[c] + xi * wr[c];
        }
    }

    const int bb = tok0 / L;               // whole block in one b (L % QT == 0)
    const int ll = (tok0 % L) + tl;
    const size_t row = ((size_t)(bb * H + h) * L + ll) * 3;   // float4 units
    #pragma unroll
    for (int sl = 0; sl < 3; ++sl) {
        F4H f;
        #pragma unroll
        for (int j = 0; j < 4; ++j)
            f.h[j] = pkrtz(d[8*sl + 2*j], d[8*sl + 2*j + 1]);
        ((float4*)dstg)[row + sl] = f.v;
    }
}

// ---------------- Kernel 2: fused banded attention + output projection ----------------
// (unchanged from R12/R16 — best measured config)
constexpr int TQ2    = 32;
constexpr int GROUPS = 4;
constexpr int CHUNK  = 25;                  // ceil(LOOKBACK/GROUPS)
constexpr int MAXK2  = TQ2 + LOOKBACK - 1;  // 131
constexpr int NT2    = L / TQ2;             // 64

__global__ __launch_bounds__(512, 2) void attn_proj_kernel(
    const __fp16* __restrict__ qg, const __fp16* __restrict__ kg,
    const __fp16* __restrict__ vg,
    const float* __restrict__ Wout_amp, const float* __restrict__ bout_amp,
    const float* __restrict__ Wout_ang_r, const float* __restrict__ Wout_ang_i,
    float* __restrict__ out)
{
    __shared__ float4 Ks[H][MAXK2][3];
    __shared__ float4 Vs[H][MAXK2][3];
    __shared__ float  att_s[TQ2][100];      // [ql][h*24 + d]

    const int tid = threadIdx.x;
    const int b   = blockIdx.x >> 6;        // NT2 = 64
    const int qt  = blockIdx.x & 63;
    const int q0  = qt * TQ2;
    int kmin = q0 - (LOOKBACK - 1); if (kmin < 0) kmin = 0;

    // ---- stage K/V for all 4 heads (full 131 rows, always in-bounds) ----
    {
        const float4* kb = (const float4*)kg;
        const float4* vb = (const float4*)vg;
        for (int c = tid; c < H * MAXK2 * 3; c += 512) {
            int hh  = c / (MAXK2 * 3);
            int rem = c % (MAXK2 * 3);
            int r   = rem / 3, sl = rem % 3;
            size_t gi = ((size_t)(b * H + hh) * L + kmin + r) * 3 + sl;
            Ks[hh][r][sl] = kb[gi];
            Vs[hh][r][sl] = vb[gi];
        }
    }
    __syncthreads();

    // ---- attention (per-wave: head h, query-half qh) ----
    const int ww   = tid >> 6;              // wave 0..7
    const int lane = tid & 63;
    const int h    = ww & 3;                // wave-uniform head
    const int qh   = ww >> 2;               // 0/1
    const int q16  = lane & 15;
    const int g    = lane >> 4;             // split-K group 0..3
    const int ql   = qh * 16 + q16;
    const int qi   = q0 + ql;

    f16x2 qhv[12];
    {
        const float4* qrow = (const float4*)qg + ((size_t)(b * H + h) * L + qi) * 3;
        F4H a0, a1, a2;
        a0.v = qrow[0]; a1.v = qrow[1]; a2.v = qrow[2];
        #pragma unroll
        for (int j = 0; j < 4; ++j) {
            qhv[j] = a0.h[j]; qhv[4 + j] = a1.h[j]; qhv[8 + j] = a2.h[j];
        }
    }

    const float scale = 0.2041241452319315f; // 1/sqrt(24)
    int j0 = qi - (LOOKBACK - 1); if (j0 < 0) j0 = 0;
    const int jstart = j0 + g;

    float sc[CHUNK];
    #pragma unroll
    for (int t = 0; t < CHUNK; ++t) {
        int j = jstart + t * GROUPS;
        int r = j - kmin;
        F4H k0, k1, k2;
        k0.v = Ks[h][r][0]; k1.v = Ks[h][r][1]; k2.v = Ks[h][r][2];
        float d = 0.f;
        #pragma unroll
        for (int jj = 0; jj < 4; ++jj) d = fdot2f(qhv[jj],     k0.h[jj], d);
        #pragma unroll
        for (int jj = 0; jj < 4; ++jj) d = fdot2f(qhv[4 + jj], k1.h[jj], d);
        #pragma unroll
        for (int jj = 0; jj < 4; ++jj) d = fdot2f(qhv[8 + jj], k2.h[jj], d);
        sc[t] = (j <= qi) ? d * scale : -3.0e38f;
    }
    float m = sc[0];
    #pragma unroll
    for (int t = 1; t < CHUNK; ++t) m = fmaxf(m, sc[t]);
    float ssum = 0.f;
    #pragma unroll
    for (int t = 0; t < CHUNK; ++t) {
        float p = __expf(sc[t] - m);
        p = (sc[t] > -1.0e37f) ? p : 0.f;
        sc[t] = p;
        ssum += p;
    }
    float o[24];
    #pragma unroll
    for (int e = 0; e < 24; ++e) o[e] = 0.f;
    #pragma unroll
    for (int t = 0; t < CHUNK; ++t) {
        float p = sc[t];
        int j = jstart + t * GROUPS;
        int r = j - kmin;
        #pragma unroll
        for (int sl = 0; sl < 3; ++sl) {
            F4H vv; vv.v = Vs[h][r][sl];
            #pragma unroll
            for (int jj = 0; jj < 4; ++jj) {
                float2 a = up2(vv.h[jj]);          // folds to v_fma_mix
                o[8*sl + 2*jj]     += p * a.x;
                o[8*sl + 2*jj + 1] += p * a.y;
            }
        }
    }

    // merge across the 4 groups (lanes xor 16, xor 32) — exact algebra
    #pragma unroll
    for (int d = 16; d <= 32; d <<= 1) {
        float m2 = __shfl_xor(m, d);
        float s2 = __shfl_xor(ssum, d);
        float mm = fmaxf(m, m2);
        float c1 = __expf(m - mm);
        float c2 = __expf(m2 - mm);
        ssum = ssum * c1 + s2 * c2;
        #pragma unroll
        for (int e = 0; e < 24; ++e)
            o[e] = o[e] * c1 + __shfl_xor(o[e], d) * c2;
        m = mm;
    }
    float inv = 1.f / ssum;

    // write att_s[ql][h*24 + d] = o[d]*inv ; duplicate lanes split 6 slots
    {
        float* arow = &att_s[ql][h * 24];
        if (g == 0) {
            *(float4*)(arow +  0) = make_float4(o[0]*inv,  o[1]*inv,  o[2]*inv,  o[3]*inv);
            *(float4*)(arow + 16) = make_float4(o[16]*inv, o[17]*inv, o[18]*inv, o[19]*inv);
        } else if (g == 1) {
            *(float4*)(arow +  4) = make_float4(o[4]*inv,  o[5]*inv,  o[6]*inv,  o[7]*inv);
            *(float4*)(arow + 20) = make_float4(o[20]*inv, o[21]*inv, o[22]*inv, o[23]*inv);
        } else if (g == 2) {
            *(float4*)(arow +  8) = make_float4(o[8]*inv,  o[9]*inv,  o[10]*inv, o[11]*inv);
        } else {
            *(float4*)(arow + 12) = make_float4(o[12]*inv, o[13]*inv, o[14]*inv, o[15]*inv);
        }
    }
    __syncthreads();

    // ---- output projection: thread = (tok, s); 5 outputs ----
    {
        constexpr size_t ANG_OUT = (size_t)NTOK * ANG; // 262144
        const int tok = tid >> 4;          // 0..31
        const int s   = tid & 15;          // 0..15
        const float* arow = att_s[tok];
        const size_t tokg = (size_t)b * L + q0 + tok;

        float accr = 0.f, acci = 0.f;
        #pragma unroll
        for (int h2 = 0; h2 < H; ++h2) {
            #pragma unroll
            for (int c = 0; c < 6; ++c) {
                float ar = arow[h2*24 + c], ai = arow[h2*24 + 6 + c];
                int rw = h2 * 6 + c;
                float wr = Wout_ang_r[rw * 16 + s];
                float wi = Wout_ang_i[rw * 16 + s];
                accr += ar * wr - ai * wi;
                acci += ar * wi + ai * wr;
            }
        }
        out[tokg * 16 + s]           = accr;
        out[ANG_OUT + tokg * 16 + s] = acci;

        float a0 = bout_amp[s], a1 = bout_amp[s + 16], a2 = bout_amp[s + 32];
        #pragma unroll
        for (int h2 = 0; h2 < H; ++h2) {
            #pragma unroll
            for (int c = 0; c < 12; ++c) {
                float xa = arow[h2*24 + 12 + c];
                const float* wrow = Wout_amp + (h2 * 12 + c) * 48;
                a0 += xa * wrow[s];
                a1 += xa * wrow[s + 16];
                a2 += xa * wrow[s + 32];
            }
        }
        float* ob = out + 2 * ANG_OUT + tokg * 48;
        ob[s]      = a0;
        ob[s + 16] = a1;
        ob[s + 32] = a2;
    }
}

// -------------------- Launch --------------------
extern "C" void kernel_launch(void* const* d_in, const int* in_sizes, int n_in,
                              void* d_out, int out_size, void* d_ws, size_t ws_size,
                              hipStream_t stream)
{
    const float* x_ang      = (const float*)d_in[0];
    const float* x_amp      = (const float*)d_in[1];
    const float* Wq_amp     = (const float*)d_in[2];
    const float* Wk_amp     = (const float*)d_in[3];
    const float* Wv_amp     = (const float*)d_in[4];
    const float* Wq_ang_r   = (const float*)d_in[5];
    const float* Wq_ang_i   = (const float*)d_in[6];
    const float* Wk_ang_r   = (const float*)d_in[7];
    const float* Wk_ang_i   = (const float*)d_in[8];
    const float* Wv_ang_r   = (const float*)d_in[9];
    const float* Wv_ang_i   = (const float*)d_in[10];
    const float* Wout_amp   = (const float*)d_in[11];
    const float* bout_amp   = (const float*)d_in[12];
    const float* Wout_ang_r = (const float*)d_in[13];
    const float* Wout_ang_i = (const float*)d_in[14];

    float* out = (float*)d_out;

    const size_t NQKV = (size_t)NTOK * H * 24;       // 1,572,864 halves each
    __fp16* qg = (__fp16*)d_ws;
    __fp16* kg = qg + NQKV;
    __fp16* vg = kg + NQKV;

    qkv7_kernel<<<QKV_BLOCKS, 256, 0, stream>>>(
        x_ang, x_amp, Wq_amp, Wk_amp, Wv_amp,
        Wq_ang_r, Wq_ang_i, Wk_ang_r, Wk_ang_i, Wv_ang_r, Wv_ang_i,
        qg, kg, vg);

    attn_proj_kernel<<<B * NT2, 512, 0, stream>>>(
        qg, kg, vg, Wout_amp, bout_amp, Wout_ang_r, Wout_ang_i, out);
}